// Round 15
// baseline (123.334 us; speedup 1.0000x reference)
//
#include <hip/hip_runtime.h>
#include <stdint.h>
#include <stddef.h>

// ---------------------------------------------------------------------------
// Fused transformer attention block for MI355X (gfx950)
//   x[2,2048,1024] fp32 -> QKV proj(+RoPE fused) -> 16-head softmax attn -> out proj
// bf16 MFMA (16x16x32), fp32 accumulate.
// R15: GEMMs -> 128x128/BK=32/4-wave gemm_bt2 with 2-bit XOR LDS swizzle
//      (slot ^= (row>>2)&3; max 2-way = free) and 32KB LDS -> 3 blocks/CU
//      (768-block grid = 3x256 exactly; m114 implicit cross-block overlap).
//      R14's 256^2 ran 192 blocks on 256 CUs (25% CUs idle, occupancy 13%).
//      attn (R13) and prep frozen.
// ---------------------------------------------------------------------------

typedef short          bf16x8 __attribute__((ext_vector_type(8)));
typedef float          f32x4  __attribute__((ext_vector_type(4)));
typedef unsigned short u16x4  __attribute__((ext_vector_type(4)));
typedef unsigned short u16x8  __attribute__((ext_vector_type(8)));

#define B_   2
#define L_   2048
#define D_   1024
#define H_   16
#define HD_  64
#define BL_  4096           // B_*L_
#define LOG2E 1.4426950408889634f
#define QSC  0.18033688011112042f   // 0.125 * LOG2E (scale+log2e folded into Q)

__device__ __forceinline__ unsigned short f2bf(float f) {   // RNE f32->bf16
  unsigned int u = __float_as_uint(f);
  u += 0x7FFFu + ((u >> 16) & 1u);
  return (unsigned short)(u >> 16);
}
__device__ __forceinline__ float bf2f(unsigned short h) {
  return __uint_as_float(((unsigned int)h) << 16);
}
__device__ __forceinline__ uint32_t cvtpk_bf16(float lo, float hi) {
  uint32_t r;
  asm("v_cvt_pk_bf16_f32 %0, %1, %2" : "=v"(r) : "v"(lo), "v"(hi));
  return r;
}
// raw v_exp_f32: D = 2^S0 (~1 ulp; inputs here are |x| < ~40, no edge cases)
__device__ __forceinline__ float fast_exp2(float x) {
  float r;
  asm("v_exp_f32 %0, %1" : "=v"(r) : "v"(x));
  return r;
}

// async global->LDS, 16B per lane; LDS dest is wave-uniform base + lane*16
__device__ __forceinline__ void gload_lds16(const unsigned short* g, unsigned short* l) {
  __builtin_amdgcn_global_load_lds(
      (__attribute__((address_space(1))) void*)g,
      (__attribute__((address_space(3))) void*)l, 16, 0, 0);
}

// ---------------------------------------------------------------------------
// Fused preprocessing (frozen): one kernel, range-partitioned grid.
// ---------------------------------------------------------------------------
__device__ __forceinline__ void transpose_tile(
    const float* __restrict__ src, unsigned short* __restrict__ dst,
    int K, int N, int n0, int k0, int tid, float (*tile)[33]) {
  const int tx = tid & 31, ty = tid >> 5;   // (32,8)
#pragma unroll
  for (int i = 0; i < 4; ++i)
    tile[ty * 4 + i][tx] = src[(size_t)(k0 + ty * 4 + i) * N + n0 + tx];
  __syncthreads();
#pragma unroll
  for (int i = 0; i < 4; ++i)
    dst[(size_t)(n0 + ty * 4 + i) * K + k0 + tx] = f2bf(tile[tx][ty * 4 + i]);
}

__global__ void __launch_bounds__(256)
prep_kernel(const float* __restrict__ x,
            const float* __restrict__ Wqkv,
            const float* __restrict__ Wout,
            u16x8* __restrict__ xb,
            unsigned short* __restrict__ WqkvT,
            unsigned short* __restrict__ WoutT,
            float2* __restrict__ rtbl) {
  __shared__ float tile[32][33];
  const int bid = blockIdx.x, tid = threadIdx.x;
  if (bid < 2048) {                       // cast x -> bf16
    const int i = bid * 256 + tid;        // 524288 total, exact
    const float4 a = ((const float4*)x)[2 * i];
    const float4 b = ((const float4*)x)[2 * i + 1];
    u16x8 o;
    o[0] = f2bf(a.x); o[1] = f2bf(a.y); o[2] = f2bf(a.z); o[3] = f2bf(a.w);
    o[4] = f2bf(b.x); o[5] = f2bf(b.y); o[6] = f2bf(b.z); o[7] = f2bf(b.w);
    xb[i] = o;
  } else if (bid < 2304) {                // RoPE table
    const int i = (bid - 2048) * 256 + tid;   // 65536
    const int pos = i >> 5, j = i & 31;
    const float inv = exp2f(-(float)j * 0.4152410118609203f);   // log2(1e4)/32
    float s, c;
    sincosf((float)pos * inv, &s, &c);
    rtbl[i] = make_float2(c, s);
  } else if (bid < 5376) {                // Wqkv transpose
    const int t = bid - 2304;             // 96 x 32
    transpose_tile(Wqkv, WqkvT, D_, 3 * D_, (t % 96) * 32, (t / 96) * 32, tid, tile);
  } else {                                // Wout transpose
    const int t = bid - 5376;             // 32 x 32
    transpose_tile(Wout, WoutT, D_, D_, (t % 32) * 32, (t / 32) * 32, tid, tile);
  }
}

// ---------------------------------------------------------------------------
// gemm_bt2 (R15): C[M][N] = A[M][K](bf16) * Bt[N][K](bf16)^T + bias.
// 128x128 tile, BK=32, 4 waves (2x2, 64x64 out each = 4x4 16x16 frags).
// LDS 32KB (2buf x (A+B) x 8KB) -> 3 blocks/CU resident; m97 2-barrier loop
// (16 MFMA + 8 ds_read_b128 per wave per K-step); 2-bit XOR swizzle
// slot' = slot ^ ((row>>2)&3) -- pre-swizzled global source + XOR on read,
// worst case 2-way bank aliasing (free, m136). XCD-swizzled 1D grid (%8==0).
// MODE 0: RoPE(Q,K)+sigma-V epilogue (verbatim from verified R8 gemm_bt).
// MODE 1: fp32 out + bias.
// ---------------------------------------------------------------------------
template <int MODE>
__global__ void __launch_bounds__(256)
gemm_bt2(const unsigned short* __restrict__ A,
         const unsigned short* __restrict__ Bt,
         const float* __restrict__ bias,
         const float2* __restrict__ rt,
         float* __restrict__ outF,
         unsigned short* __restrict__ Qb,
         unsigned short* __restrict__ Kb,
         unsigned short* __restrict__ Vt,
         int M, int N, int K) {
  __shared__ unsigned short As[2][128 * 32];   // [buf][row 128][k 32] swizzled
  __shared__ unsigned short Bs[2][128 * 32];
  const int tid = threadIdx.x;
  const int w = tid >> 6, l = tid & 63;
  const int lg = l >> 4, ll = l & 15;
  // T1: XCD-aware remap of the linearized grid (gridDim.x % 8 == 0)
  const int cpx = gridDim.x >> 3;
  const int lid = (blockIdx.x & 7) * cpx + (blockIdx.x >> 3);
  const int nx = N >> 7;
  const int n0 = (lid % nx) * 128, m0 = (lid / nx) * 128;
  const int wm = (w >> 1) * 64, wn = (w & 1) * 64;

  f32x4 acc[4][4] = {};

  // staging: slot idx = c*256 + tid covers (row = idx>>2, 16B-slot j = idx&3);
  // source col pre-swizzled (j ^ ((row>>2)&3)) so linear-LDS + XOR-read works.
  int srcOff[2];
#pragma unroll
  for (int c = 0; c < 2; ++c) {
    const int idx = c * 256 + tid;
    const int row = idx >> 2, j = idx & 3;
    srcOff[c] = row * K + ((j ^ ((row >> 2) & 3)) << 3);   // ushort offset
  }
  const unsigned short* gA = A + (size_t)m0 * K;
  const unsigned short* gB = Bt + (size_t)n0 * K;

  auto stage = [&](int bsel, int kt) {
    const int kk = kt * 32;
#pragma unroll
    for (int c = 0; c < 2; ++c) {
      gload_lds16(gA + srcOff[c] + kk, &As[bsel][c * 2048 + w * 512]);
      gload_lds16(gB + srcOff[c] + kk, &Bs[bsel][c * 2048 + w * 512]);
    }
  };

  const int NT = K >> 5;
  int buf = 0;

  stage(0, 0);
  for (int kt = 0; kt < NT; ++kt) {
    __syncthreads();                      // drains vmcnt -> staged tile visible
    if (kt + 1 < NT) stage(buf ^ 1, kt + 1);
    const char* pa = (const char*)&As[buf][0];
    const char* pb = (const char*)&Bs[buf][0];
    bf16x8 af[4], bfv[4];
#pragma unroll
    for (int mi = 0; mi < 4; ++mi) {
      const int row = wm + mi * 16 + ll;
      af[mi] = *(const bf16x8*)(pa + row * 64 + ((lg * 16) ^ (((row >> 2) & 3) << 4)));
    }
#pragma unroll
    for (int ni = 0; ni < 4; ++ni) {
      const int row = wn + ni * 16 + ll;
      bfv[ni] = *(const bf16x8*)(pb + row * 64 + ((lg * 16) ^ (((row >> 2) & 3) << 4)));
    }
    __builtin_amdgcn_s_setprio(1);
#pragma unroll
    for (int mi = 0; mi < 4; ++mi)
#pragma unroll
      for (int ni = 0; ni < 4; ++ni)
        acc[mi][ni] = __builtin_amdgcn_mfma_f32_16x16x32_bf16(
            af[mi], bfv[ni], acc[mi][ni], 0, 0, 0);
    __builtin_amdgcn_s_setprio(0);
    buf ^= 1;
  }

  // epilogue. C layout: row = (l>>4)*4 + reg, col = l&15   (guide m89/m91)
  if (MODE == 0) {
    const int t = (n0 + wn) >> 10;        // 0=q 1=k 2=v, wave-uniform (64 | 1024)
    if (t == 2) {                         // V: sigma-permuted transpose
#pragma unroll
      for (int ni = 0; ni < 4; ++ni) {
        const int n = n0 + wn + ni * 16 + ll;
        const float bv = bias[n];
        const int r = n & 1023;
        const int h = r >> 6, d = r & 63;
#pragma unroll
        for (int mi = 0; mi < 4; ++mi) {
          const int row0 = m0 + wm + mi * 16 + lg * 4;
          const int b   = row0 >> 11;
          const int pos = row0 & 2047;    // 4-aligned
          const int bh  = b * H_ + h;
          const int wb  = (pos >> 2) & 7;
          const int posS = (pos & ~31) + 8 * (wb & 3) + 4 * (wb >> 2);
          u16x4 pk;
#pragma unroll
          for (int rg = 0; rg < 4; ++rg) pk[rg] = f2bf(acc[mi][ni][rg] + bv);
          *(u16x4*)(Vt + ((size_t)bh * HD_ + d) * L_ + posS) = pk;
        }
      }
    } else {                              // Q/K: fused RoPE via table, pairs (d, d+32)
      unsigned short* dst = (t == 0) ? Qb : Kb;
      const float qsc = (t == 0) ? QSC : 1.0f;
      const int h = ((n0 + wn) & 1023) >> 6;   // wave-uniform
#pragma unroll
      for (int ni = 0; ni < 2; ++ni) {
        const int d = ni * 16 + ll;       // 0..31
        const float bv1 = bias[n0 + wn + ni * 16 + ll];
        const float bv2 = bias[n0 + wn + (ni + 2) * 16 + ll];
#pragma unroll
        for (int mi = 0; mi < 4; ++mi) {
          const int row0 = m0 + wm + mi * 16 + lg * 4;
          const int b   = row0 >> 11;
          const int pos0 = row0 & 2047;
          unsigned short* base = dst + (size_t)(b * H_ + h) * L_ * HD_;
#pragma unroll
          for (int rg = 0; rg < 4; ++rg) {
            const int pos = pos0 + rg;
            const float2 cs = rt[pos * 32 + d];
            const float q1 = acc[mi][ni][rg] + bv1;
            const float q2 = acc[mi][ni + 2][rg] + bv2;
            base[(size_t)pos * HD_ + d]      = f2bf((q1 * cs.x - q2 * cs.y) * qsc);
            base[(size_t)pos * HD_ + d + 32] = f2bf((q2 * cs.x + q1 * cs.y) * qsc);
          }
        }
      }
    }
  } else {
#pragma unroll
    for (int ni = 0; ni < 4; ++ni) {
      const int n = n0 + wn + ni * 16 + ll;
      const float bv = bias[n];
#pragma unroll
      for (int mi = 0; mi < 4; ++mi) {
        const int row0 = m0 + wm + mi * 16 + lg * 4;
#pragma unroll
        for (int rg = 0; rg < 4; ++rg)
          outF[(size_t)(row0 + rg) * N + n] = acc[mi][ni][rg] + bv;
      }
    }
  }
}

// ---------------------------------------------------------------------------
// Flash attention (R13, frozen): 8 waves x 16 q-rows; KVBLK=128 as 2x[64][64]
// chunks; swapped QK^T; in-register P; sigma-permuted Vt; no-max softmax;
// raw v_exp_f32; row sum via osum = mfma(pa, ones).
// ---------------------------------------------------------------------------
__global__ void __launch_bounds__(512)
attn_kernel(const unsigned short* __restrict__ Qb,
            const unsigned short* __restrict__ Kb,
            const unsigned short* __restrict__ Vt,
            unsigned short* __restrict__ Ob) {
  __shared__ unsigned short Ks[2][2][4096];  // [buf][kc][kv 64][d 64], swizzled
  __shared__ unsigned short Vs[2][2][4096];  // [buf][kc][d 64][kv' 64], swizzled
  const int tid = threadIdx.x, w = tid >> 6, l = tid & 63;
  const int lg = l >> 4, ll = l & 15;
  const int bid = ((blockIdx.x & 7) << 6) + (blockIdx.x >> 3);
  const int bh  = bid >> 4;
  const int q0  = (bid & 15) * 128;
  const unsigned short* Qp = Qb + ((size_t)bh * L_ + q0 + w * 16) * HD_;
  const unsigned short* Kp = Kb + (size_t)bh * L_ * HD_;
  const unsigned short* Vp = Vt + (size_t)bh * HD_ * L_;

  const int srow = tid >> 3;
  const int scol = ((tid & 7) ^ (srow & 7)) * 8;
  auto stage = [&](int bsel, int kv0) {
#pragma unroll
    for (int c = 0; c < 2; ++c) {
      gload_lds16(Kp + (size_t)(kv0 + c * 64 + srow) * HD_ + scol, &Ks[bsel][c][w * 512]);
      gload_lds16(Vp + (size_t)srow * L_ + kv0 + c * 64 + scol, &Vs[bsel][c][w * 512]);
    }
  };

  bf16x8 qf[2];
#pragma unroll
  for (int ks = 0; ks < 2; ++ks)
    qf[ks] = *(const bf16x8*)(Qp + (size_t)ll * HD_ + ks * 32 + 8 * lg);

  bf16x8 ones;
#pragma unroll
  for (int j = 0; j < 8; ++j) ones[j] = (short)0x3F80;

  f32x4 o[4] = {};
  f32x4 osum = {};                           // row-sum acc: osum[rg] for q=lg*4+rg

  stage(0, 0);
  __syncthreads();

  int buf = 0;
  for (int t = 0; t < 16; ++t) {
    if (t + 1 < 16) stage(buf ^ 1, (t + 1) * 128);
    f32x4 s[2][4];

#pragma unroll
    for (int kc = 0; kc < 2; ++kc) {
      const char* Ksb = (const char*)&Ks[buf][kc][0];
      bf16x8 kfr[4][2];
#pragma unroll
      for (int ni = 0; ni < 4; ++ni)
#pragma unroll
        for (int ks = 0; ks < 2; ++ks)
          kfr[ni][ks] = *(const bf16x8*)(Ksb + (ni * 16 + ll) * 128 +
                                         ((ks * 64 + lg * 16) ^ ((ll & 7) << 4)));
#pragma unroll
      for (int ni = 0; ni < 4; ++ni) s[kc][ni] = f32x4{0.f, 0.f, 0.f, 0.f};
      __builtin_amdgcn_s_setprio(1);
#pragma unroll
      for (int ks = 0; ks < 2; ++ks)
#pragma unroll
        for (int ni = 0; ni < 4; ++ni)
          s[kc][ni] = __builtin_amdgcn_mfma_f32_16x16x32_bf16(kfr[ni][ks], qf[ks], s[kc][ni], 0, 0, 0);
      __builtin_amdgcn_s_setprio(0);
    }

    bf16x8 pa[2][2];                       // [kc][ks]
#pragma unroll
    for (int kc = 0; kc < 2; ++kc) {
      uint32_t wd[4][2];
#pragma unroll
      for (int ni = 0; ni < 4; ++ni) {
        const float p0 = fast_exp2(s[kc][ni][0]);
        const float p1 = fast_exp2(s[kc][ni][1]);
        const float p2 = fast_exp2(s[kc][ni][2]);
        const float p3 = fast_exp2(s[kc][ni][3]);
        wd[ni][0] = cvtpk_bf16(p0, p1);
        wd[ni][1] = cvtpk_bf16(p2, p3);
      }
#pragma unroll
      for (int ks = 0; ks < 2; ++ks) {
        union { uint32_t u[4]; bf16x8 v; } pu;
        pu.u[0] = wd[2 * ks][0];     pu.u[1] = wd[2 * ks][1];
        pu.u[2] = wd[2 * ks + 1][0]; pu.u[3] = wd[2 * ks + 1][1];
        pa[kc][ks] = pu.v;
      }
    }

#pragma unroll
    for (int kc = 0; kc < 2; ++kc) {
      const char* Vsb = (const char*)&Vs[buf][kc][0];
      bf16x8 vf[2][4];
#pragma unroll
      for (int ks = 0; ks < 2; ++ks)
#pragma unroll
        for (int ni = 0; ni < 4; ++ni)
          vf[ks][ni] = *(const bf16x8*)(Vsb + (ni * 16 + ll) * 128 +
                                        ((ks * 64 + lg * 16) ^ ((ll & 7) << 4)));
      __builtin_amdgcn_s_setprio(1);
#pragma unroll
      for (int ks = 0; ks < 2; ++ks) {
#pragma unroll
        for (int ni = 0; ni < 4; ++ni)
          o[ni] = __builtin_amdgcn_mfma_f32_16x16x32_bf16(pa[kc][ks], vf[ks][ni], o[ni], 0, 0, 0);
        osum = __builtin_amdgcn_mfma_f32_16x16x32_bf16(pa[kc][ks], ones, osum, 0, 0, 0);
      }
      __builtin_amdgcn_s_setprio(0);
    }

    __syncthreads();
    buf ^= 1;
  }

  const int b = bh >> 4, h = bh & 15;
  unsigned short* Op = Ob + ((size_t)b * L_ + q0 + w * 16) * D_ + h * HD_;
#pragma unroll
  for (int rg = 0; rg < 4; ++rg) {
    const float iq = 1.0f / osum[rg];
#pragma unroll
    for (int ni = 0; ni < 4; ++ni)
      Op[(size_t)(lg * 4 + rg) * D_ + ni * 16 + ll] = f2bf(o[ni][rg] * iq);
  }
}

// ---------------------------------------------------------------------------
extern "C" void kernel_launch(void* const* d_in, const int* in_sizes, int n_in,
                              void* d_out, int out_size, void* d_ws, size_t ws_size,
                              hipStream_t stream) {
  const float* x    = (const float*)d_in[0];
  const float* Wqkv = (const float*)d_in[1];
  const float* bqkv = (const float*)d_in[2];
  const float* Wout = (const float*)d_in[3];
  const float* bout = (const float*)d_in[4];
  float* out = (float*)d_out;

  char* ws = (char*)d_ws;                       // 48 MiB used
  unsigned short* xb    = (unsigned short*)(ws);                    // 8 MiB
  unsigned short* WqkvT = (unsigned short*)(ws + (8ull  << 20));    // 6 MiB
  unsigned short* WoutT = (unsigned short*)(ws + (14ull << 20));    // 2 MiB
  unsigned short* Qb    = (unsigned short*)(ws + (16ull << 20));    // 8 MiB
  unsigned short* Kb    = (unsigned short*)(ws + (24ull << 20));    // 8 MiB
  unsigned short* Vt    = (unsigned short*)(ws + (32ull << 20));    // 8 MiB
  unsigned short* Ob    = (unsigned short*)(ws + (40ull << 20));    // 8 MiB
  float2* rtbl = (float2*)(ws + (40ull << 20));  // aliases Ob (dead by attn)

  prep_kernel<<<6400, 256, 0, stream>>>(x, Wqkv, Wout, (u16x8*)xb, WqkvT, WoutT, rtbl);

  gemm_bt2<0><<<(3 * D_ / 128) * (BL_ / 128), 256, 0, stream>>>(
      xb, WqkvT, bqkv, rtbl, nullptr, Qb, Kb, Vt, BL_, 3 * D_, D_);

  attn_kernel<<<B_ * H_ * (L_ / 128), 512, 0, stream>>>(Qb, Kb, Vt, Ob);

  gemm_bt2<1><<<(D_ / 128) * (BL_ / 128), 256, 0, stream>>>(
      Ob, WoutT, bout, nullptr, out, nullptr, nullptr, nullptr, BL_, D_, D_);
}

// Round 16
// 109.952 us; speedup vs baseline: 1.1217x; 1.1217x over previous
//
#include <hip/hip_runtime.h>
#include <stdint.h>
#include <stddef.h>

// ---------------------------------------------------------------------------
// Fused transformer attention block for MI355X (gfx950)
//   x[2,2048,1024] fp32 -> QKV proj(+RoPE fused) -> 16-head softmax attn -> out proj
// bf16 MFMA (16x16x32), fp32 accumulate.
// R16: GEMMs -> 128x128 / BK=64 / 4 waves. Rows are 128B so the R14-proven
//      (row&7)<<4 XOR swizzle applies byte-identically (0 conflicts measured);
//      DS efficiency 16K MACs/b128 (4x R15's BK=32); LDS 64KB -> 2 blocks/CU;
//      grid 768 = 3x256 exactly (m114 cross-block overlap). R15's 2-bit
//      swizzle on 64B rows was wrong (3.1M conflicts) - reverted.
//      attn (R13) and prep frozen.
// ---------------------------------------------------------------------------

typedef short          bf16x8 __attribute__((ext_vector_type(8)));
typedef float          f32x4  __attribute__((ext_vector_type(4)));
typedef unsigned short u16x4  __attribute__((ext_vector_type(4)));
typedef unsigned short u16x8  __attribute__((ext_vector_type(8)));

#define B_   2
#define L_   2048
#define D_   1024
#define H_   16
#define HD_  64
#define BL_  4096           // B_*L_
#define LOG2E 1.4426950408889634f
#define QSC  0.18033688011112042f   // 0.125 * LOG2E (scale+log2e folded into Q)

__device__ __forceinline__ unsigned short f2bf(float f) {   // RNE f32->bf16
  unsigned int u = __float_as_uint(f);
  u += 0x7FFFu + ((u >> 16) & 1u);
  return (unsigned short)(u >> 16);
}
__device__ __forceinline__ float bf2f(unsigned short h) {
  return __uint_as_float(((unsigned int)h) << 16);
}
__device__ __forceinline__ uint32_t cvtpk_bf16(float lo, float hi) {
  uint32_t r;
  asm("v_cvt_pk_bf16_f32 %0, %1, %2" : "=v"(r) : "v"(lo), "v"(hi));
  return r;
}
// raw v_exp_f32: D = 2^S0 (~1 ulp; inputs here are |x| < ~40, no edge cases)
__device__ __forceinline__ float fast_exp2(float x) {
  float r;
  asm("v_exp_f32 %0, %1" : "=v"(r) : "v"(x));
  return r;
}

// async global->LDS, 16B per lane; LDS dest is wave-uniform base + lane*16
__device__ __forceinline__ void gload_lds16(const unsigned short* g, unsigned short* l) {
  __builtin_amdgcn_global_load_lds(
      (__attribute__((address_space(1))) void*)g,
      (__attribute__((address_space(3))) void*)l, 16, 0, 0);
}

// ---------------------------------------------------------------------------
// Fused preprocessing (frozen): one kernel, range-partitioned grid.
// ---------------------------------------------------------------------------
__device__ __forceinline__ void transpose_tile(
    const float* __restrict__ src, unsigned short* __restrict__ dst,
    int K, int N, int n0, int k0, int tid, float (*tile)[33]) {
  const int tx = tid & 31, ty = tid >> 5;   // (32,8)
#pragma unroll
  for (int i = 0; i < 4; ++i)
    tile[ty * 4 + i][tx] = src[(size_t)(k0 + ty * 4 + i) * N + n0 + tx];
  __syncthreads();
#pragma unroll
  for (int i = 0; i < 4; ++i)
    dst[(size_t)(n0 + ty * 4 + i) * K + k0 + tx] = f2bf(tile[tx][ty * 4 + i]);
}

__global__ void __launch_bounds__(256)
prep_kernel(const float* __restrict__ x,
            const float* __restrict__ Wqkv,
            const float* __restrict__ Wout,
            u16x8* __restrict__ xb,
            unsigned short* __restrict__ WqkvT,
            unsigned short* __restrict__ WoutT,
            float2* __restrict__ rtbl) {
  __shared__ float tile[32][33];
  const int bid = blockIdx.x, tid = threadIdx.x;
  if (bid < 2048) {                       // cast x -> bf16
    const int i = bid * 256 + tid;        // 524288 total, exact
    const float4 a = ((const float4*)x)[2 * i];
    const float4 b = ((const float4*)x)[2 * i + 1];
    u16x8 o;
    o[0] = f2bf(a.x); o[1] = f2bf(a.y); o[2] = f2bf(a.z); o[3] = f2bf(a.w);
    o[4] = f2bf(b.x); o[5] = f2bf(b.y); o[6] = f2bf(b.z); o[7] = f2bf(b.w);
    xb[i] = o;
  } else if (bid < 2304) {                // RoPE table
    const int i = (bid - 2048) * 256 + tid;   // 65536
    const int pos = i >> 5, j = i & 31;
    const float inv = exp2f(-(float)j * 0.4152410118609203f);   // log2(1e4)/32
    float s, c;
    sincosf((float)pos * inv, &s, &c);
    rtbl[i] = make_float2(c, s);
  } else if (bid < 5376) {                // Wqkv transpose
    const int t = bid - 2304;             // 96 x 32
    transpose_tile(Wqkv, WqkvT, D_, 3 * D_, (t % 96) * 32, (t / 96) * 32, tid, tile);
  } else {                                // Wout transpose
    const int t = bid - 5376;             // 32 x 32
    transpose_tile(Wout, WoutT, D_, D_, (t % 32) * 32, (t / 32) * 32, tid, tile);
  }
}

// ---------------------------------------------------------------------------
// gemm_bt3 (R16): C[M][N] = A[M][K](bf16) * Bt[N][K](bf16)^T + bias.
// 128x128 tile, BK=64, 4 waves (2x2, 64x64 out each = 4x4 16x16 frags).
// Rows = 64 k x 2B = 128B -> R14-proven XOR swizzle byte ^= (row&7)<<4
// (pre-swizzled global source + XOR on read; measured 0 conflicts).
// LDS 64KB (2buf x (16KB A + 16KB B)) -> 2 blocks/CU. m97 2-barrier loop,
// 16 K-iters, 8 gload_lds16/thread/iter. XCD-swizzled 1D grid (%8==0).
// MODE 0: RoPE(Q,K)+sigma-V epilogue (verbatim from verified R8 gemm_bt).
// MODE 1: fp32 out + bias.
// ---------------------------------------------------------------------------
template <int MODE>
__global__ void __launch_bounds__(256)
gemm_bt3(const unsigned short* __restrict__ A,
         const unsigned short* __restrict__ Bt,
         const float* __restrict__ bias,
         const float2* __restrict__ rt,
         float* __restrict__ outF,
         unsigned short* __restrict__ Qb,
         unsigned short* __restrict__ Kb,
         unsigned short* __restrict__ Vt,
         int M, int N, int K) {
  __shared__ unsigned short As[2][8192];   // [buf][128 rows][64 k] bf16, swz
  __shared__ unsigned short Bs[2][8192];
  const int tid = threadIdx.x;
  const int w = tid >> 6, l = tid & 63;
  const int lg = l >> 4, ll = l & 15;
  // T1: XCD-aware remap of the linearized grid (gridDim.x % 8 == 0)
  const int cpx = gridDim.x >> 3;
  const int lid = (blockIdx.x & 7) * cpx + (blockIdx.x >> 3);
  const int nx = N >> 7;
  const int n0 = (lid % nx) * 128, m0 = (lid / nx) * 128;
  const int wm = (w >> 1) * 64, wn = (w & 1) * 64;

  f32x4 acc[4][4] = {};

  // staging: slot idx = c*256 + tid -> row = idx>>3 (0..127), slot = idx&7;
  // source col pre-swizzled (slot ^ (row&7)) so linear-LDS + XOR-read works.
  int srcOff[4];
#pragma unroll
  for (int c = 0; c < 4; ++c) {
    const int idx = c * 256 + tid;
    const int row = idx >> 3, slot = idx & 7;
    srcOff[c] = row * K + ((slot ^ (row & 7)) << 3);   // ushort offset
  }
  const unsigned short* gA = A + (size_t)m0 * K;
  const unsigned short* gB = Bt + (size_t)n0 * K;

  auto stage = [&](int bsel, int kt) {
    const int kk = kt * 64;
#pragma unroll
    for (int c = 0; c < 4; ++c)
      gload_lds16(gA + srcOff[c] + kk, &As[bsel][c * 2048 + w * 512]);
#pragma unroll
    for (int c = 0; c < 4; ++c)
      gload_lds16(gB + srcOff[c] + kk, &Bs[bsel][c * 2048 + w * 512]);
  };

  const int NT = K >> 6;                   // 16
  int buf = 0;

  stage(0, 0);
  for (int kt = 0; kt < NT; ++kt) {
    __syncthreads();                      // drains vmcnt -> staged tile visible
    if (kt + 1 < NT) stage(buf ^ 1, kt + 1);
    const char* pa = (const char*)&As[buf][0];
    const char* pb = (const char*)&Bs[buf][0];
#pragma unroll
    for (int kk = 0; kk < 2; ++kk) {
      bf16x8 af[4], bfv[4];
#pragma unroll
      for (int mi = 0; mi < 4; ++mi) {
        const int row = wm + mi * 16 + ll;
        af[mi] = *(const bf16x8*)(pa + row * 128 +
                                  ((kk * 64 + lg * 16) ^ ((row & 7) << 4)));
      }
#pragma unroll
      for (int ni = 0; ni < 4; ++ni) {
        const int row = wn + ni * 16 + ll;
        bfv[ni] = *(const bf16x8*)(pb + row * 128 +
                                   ((kk * 64 + lg * 16) ^ ((row & 7) << 4)));
      }
      __builtin_amdgcn_s_setprio(1);
#pragma unroll
      for (int mi = 0; mi < 4; ++mi)
#pragma unroll
        for (int ni = 0; ni < 4; ++ni)
          acc[mi][ni] = __builtin_amdgcn_mfma_f32_16x16x32_bf16(
              af[mi], bfv[ni], acc[mi][ni], 0, 0, 0);
      __builtin_amdgcn_s_setprio(0);
    }
    buf ^= 1;
  }

  // epilogue. C layout: row = (l>>4)*4 + reg, col = l&15   (guide m89/m91)
  if (MODE == 0) {
    const int t = (n0 + wn) >> 10;        // 0=q 1=k 2=v, wave-uniform (64 | 1024)
    if (t == 2) {                         // V: sigma-permuted transpose
#pragma unroll
      for (int ni = 0; ni < 4; ++ni) {
        const int n = n0 + wn + ni * 16 + ll;
        const float bv = bias[n];
        const int r = n & 1023;
        const int h = r >> 6, d = r & 63;
#pragma unroll
        for (int mi = 0; mi < 4; ++mi) {
          const int row0 = m0 + wm + mi * 16 + lg * 4;
          const int b   = row0 >> 11;
          const int pos = row0 & 2047;    // 4-aligned
          const int bh  = b * H_ + h;
          const int wb  = (pos >> 2) & 7;
          const int posS = (pos & ~31) + 8 * (wb & 3) + 4 * (wb >> 2);
          u16x4 pk;
#pragma unroll
          for (int rg = 0; rg < 4; ++rg) pk[rg] = f2bf(acc[mi][ni][rg] + bv);
          *(u16x4*)(Vt + ((size_t)bh * HD_ + d) * L_ + posS) = pk;
        }
      }
    } else {                              // Q/K: fused RoPE via table, pairs (d, d+32)
      unsigned short* dst = (t == 0) ? Qb : Kb;
      const float qsc = (t == 0) ? QSC : 1.0f;
      const int h = ((n0 + wn) & 1023) >> 6;   // wave-uniform
#pragma unroll
      for (int ni = 0; ni < 2; ++ni) {
        const int d = ni * 16 + ll;       // 0..31
        const float bv1 = bias[n0 + wn + ni * 16 + ll];
        const float bv2 = bias[n0 + wn + (ni + 2) * 16 + ll];
#pragma unroll
        for (int mi = 0; mi < 4; ++mi) {
          const int row0 = m0 + wm + mi * 16 + lg * 4;
          const int b   = row0 >> 11;
          const int pos0 = row0 & 2047;
          unsigned short* base = dst + (size_t)(b * H_ + h) * L_ * HD_;
#pragma unroll
          for (int rg = 0; rg < 4; ++rg) {
            const int pos = pos0 + rg;
            const float2 cs = rt[pos * 32 + d];
            const float q1 = acc[mi][ni][rg] + bv1;
            const float q2 = acc[mi][ni + 2][rg] + bv2;
            base[(size_t)pos * HD_ + d]      = f2bf((q1 * cs.x - q2 * cs.y) * qsc);
            base[(size_t)pos * HD_ + d + 32] = f2bf((q2 * cs.x + q1 * cs.y) * qsc);
          }
        }
      }
    }
  } else {
#pragma unroll
    for (int ni = 0; ni < 4; ++ni) {
      const int n = n0 + wn + ni * 16 + ll;
      const float bv = bias[n];
#pragma unroll
      for (int mi = 0; mi < 4; ++mi) {
        const int row0 = m0 + wm + mi * 16 + lg * 4;
#pragma unroll
        for (int rg = 0; rg < 4; ++rg)
          outF[(size_t)(row0 + rg) * N + n] = acc[mi][ni][rg] + bv;
      }
    }
  }
}

// ---------------------------------------------------------------------------
// Flash attention (R13, frozen): 8 waves x 16 q-rows; KVBLK=128 as 2x[64][64]
// chunks; swapped QK^T; in-register P; sigma-permuted Vt; no-max softmax;
// raw v_exp_f32; row sum via osum = mfma(pa, ones).
// ---------------------------------------------------------------------------
__global__ void __launch_bounds__(512)
attn_kernel(const unsigned short* __restrict__ Qb,
            const unsigned short* __restrict__ Kb,
            const unsigned short* __restrict__ Vt,
            unsigned short* __restrict__ Ob) {
  __shared__ unsigned short Ks[2][2][4096];  // [buf][kc][kv 64][d 64], swizzled
  __shared__ unsigned short Vs[2][2][4096];  // [buf][kc][d 64][kv' 64], swizzled
  const int tid = threadIdx.x, w = tid >> 6, l = tid & 63;
  const int lg = l >> 4, ll = l & 15;
  const int bid = ((blockIdx.x & 7) << 6) + (blockIdx.x >> 3);
  const int bh  = bid >> 4;
  const int q0  = (bid & 15) * 128;
  const unsigned short* Qp = Qb + ((size_t)bh * L_ + q0 + w * 16) * HD_;
  const unsigned short* Kp = Kb + (size_t)bh * L_ * HD_;
  const unsigned short* Vp = Vt + (size_t)bh * HD_ * L_;

  const int srow = tid >> 3;
  const int scol = ((tid & 7) ^ (srow & 7)) * 8;
  auto stage = [&](int bsel, int kv0) {
#pragma unroll
    for (int c = 0; c < 2; ++c) {
      gload_lds16(Kp + (size_t)(kv0 + c * 64 + srow) * HD_ + scol, &Ks[bsel][c][w * 512]);
      gload_lds16(Vp + (size_t)srow * L_ + kv0 + c * 64 + scol, &Vs[bsel][c][w * 512]);
    }
  };

  bf16x8 qf[2];
#pragma unroll
  for (int ks = 0; ks < 2; ++ks)
    qf[ks] = *(const bf16x8*)(Qp + (size_t)ll * HD_ + ks * 32 + 8 * lg);

  bf16x8 ones;
#pragma unroll
  for (int j = 0; j < 8; ++j) ones[j] = (short)0x3F80;

  f32x4 o[4] = {};
  f32x4 osum = {};                           // row-sum acc: osum[rg] for q=lg*4+rg

  stage(0, 0);
  __syncthreads();

  int buf = 0;
  for (int t = 0; t < 16; ++t) {
    if (t + 1 < 16) stage(buf ^ 1, (t + 1) * 128);
    f32x4 s[2][4];

#pragma unroll
    for (int kc = 0; kc < 2; ++kc) {
      const char* Ksb = (const char*)&Ks[buf][kc][0];
      bf16x8 kfr[4][2];
#pragma unroll
      for (int ni = 0; ni < 4; ++ni)
#pragma unroll
        for (int ks = 0; ks < 2; ++ks)
          kfr[ni][ks] = *(const bf16x8*)(Ksb + (ni * 16 + ll) * 128 +
                                         ((ks * 64 + lg * 16) ^ ((ll & 7) << 4)));
#pragma unroll
      for (int ni = 0; ni < 4; ++ni) s[kc][ni] = f32x4{0.f, 0.f, 0.f, 0.f};
      __builtin_amdgcn_s_setprio(1);
#pragma unroll
      for (int ks = 0; ks < 2; ++ks)
#pragma unroll
        for (int ni = 0; ni < 4; ++ni)
          s[kc][ni] = __builtin_amdgcn_mfma_f32_16x16x32_bf16(kfr[ni][ks], qf[ks], s[kc][ni], 0, 0, 0);
      __builtin_amdgcn_s_setprio(0);
    }

    bf16x8 pa[2][2];                       // [kc][ks]
#pragma unroll
    for (int kc = 0; kc < 2; ++kc) {
      uint32_t wd[4][2];
#pragma unroll
      for (int ni = 0; ni < 4; ++ni) {
        const float p0 = fast_exp2(s[kc][ni][0]);
        const float p1 = fast_exp2(s[kc][ni][1]);
        const float p2 = fast_exp2(s[kc][ni][2]);
        const float p3 = fast_exp2(s[kc][ni][3]);
        wd[ni][0] = cvtpk_bf16(p0, p1);
        wd[ni][1] = cvtpk_bf16(p2, p3);
      }
#pragma unroll
      for (int ks = 0; ks < 2; ++ks) {
        union { uint32_t u[4]; bf16x8 v; } pu;
        pu.u[0] = wd[2 * ks][0];     pu.u[1] = wd[2 * ks][1];
        pu.u[2] = wd[2 * ks + 1][0]; pu.u[3] = wd[2 * ks + 1][1];
        pa[kc][ks] = pu.v;
      }
    }

#pragma unroll
    for (int kc = 0; kc < 2; ++kc) {
      const char* Vsb = (const char*)&Vs[buf][kc][0];
      bf16x8 vf[2][4];
#pragma unroll
      for (int ks = 0; ks < 2; ++ks)
#pragma unroll
        for (int ni = 0; ni < 4; ++ni)
          vf[ks][ni] = *(const bf16x8*)(Vsb + (ni * 16 + ll) * 128 +
                                        ((ks * 64 + lg * 16) ^ ((ll & 7) << 4)));
      __builtin_amdgcn_s_setprio(1);
#pragma unroll
      for (int ks = 0; ks < 2; ++ks) {
#pragma unroll
        for (int ni = 0; ni < 4; ++ni)
          o[ni] = __builtin_amdgcn_mfma_f32_16x16x32_bf16(pa[kc][ks], vf[ks][ni], o[ni], 0, 0, 0);
        osum = __builtin_amdgcn_mfma_f32_16x16x32_bf16(pa[kc][ks], ones, osum, 0, 0, 0);
      }
      __builtin_amdgcn_s_setprio(0);
    }

    __syncthreads();
    buf ^= 1;
  }

  const int b = bh >> 4, h = bh & 15;
  unsigned short* Op = Ob + ((size_t)b * L_ + q0 + w * 16) * D_ + h * HD_;
#pragma unroll
  for (int rg = 0; rg < 4; ++rg) {
    const float iq = 1.0f / osum[rg];
#pragma unroll
    for (int ni = 0; ni < 4; ++ni)
      Op[(size_t)(lg * 4 + rg) * D_ + ni * 16 + ll] = f2bf(o[ni][rg] * iq);
  }
}

// ---------------------------------------------------------------------------
extern "C" void kernel_launch(void* const* d_in, const int* in_sizes, int n_in,
                              void* d_out, int out_size, void* d_ws, size_t ws_size,
                              hipStream_t stream) {
  const float* x    = (const float*)d_in[0];
  const float* Wqkv = (const float*)d_in[1];
  const float* bqkv = (const float*)d_in[2];
  const float* Wout = (const float*)d_in[3];
  const float* bout = (const float*)d_in[4];
  float* out = (float*)d_out;

  char* ws = (char*)d_ws;                       // 48 MiB used
  unsigned short* xb    = (unsigned short*)(ws);                    // 8 MiB
  unsigned short* WqkvT = (unsigned short*)(ws + (8ull  << 20));    // 6 MiB
  unsigned short* WoutT = (unsigned short*)(ws + (14ull << 20));    // 2 MiB
  unsigned short* Qb    = (unsigned short*)(ws + (16ull << 20));    // 8 MiB
  unsigned short* Kb    = (unsigned short*)(ws + (24ull << 20));    // 8 MiB
  unsigned short* Vt    = (unsigned short*)(ws + (32ull << 20));    // 8 MiB
  unsigned short* Ob    = (unsigned short*)(ws + (40ull << 20));    // 8 MiB
  float2* rtbl = (float2*)(ws + (40ull << 20));  // aliases Ob (dead by attn)

  prep_kernel<<<6400, 256, 0, stream>>>(x, Wqkv, Wout, (u16x8*)xb, WqkvT, WoutT, rtbl);

  gemm_bt3<0><<<(3 * D_ / 128) * (BL_ / 128), 256, 0, stream>>>(
      xb, WqkvT, bqkv, rtbl, nullptr, Qb, Kb, Vt, BL_, 3 * D_, D_);

  attn_kernel<<<B_ * H_ * (L_ / 128), 512, 0, stream>>>(Qb, Kb, Vt, Ob);

  gemm_bt3<1><<<(D_ / 128) * (BL_ / 128), 256, 0, stream>>>(
      Ob, WoutT, bout, nullptr, out, nullptr, nullptr, nullptr, BL_, D_, D_);
}

// Round 17
// 109.423 us; speedup vs baseline: 1.1271x; 1.0048x over previous
//
#include <hip/hip_runtime.h>
#include <stdint.h>
#include <stddef.h>

// ---------------------------------------------------------------------------
// Fused transformer attention block for MI355X (gfx950)
//   x[2,2048,1024] fp32 -> QKV proj(+RoPE fused) -> 16-head softmax attn -> out proj
// bf16 MFMA (16x16x32), fp32 accumulate.
// R17: GEMM1 epilogue staged through LDS (reuse dead As/Bs; per-wave 64x72
//      u16 tile) -> Q/K written as contiguous 1KB bursts, V as 128B bursts
//      (was 64x 2B scattered + 16x 8B @4KB stride per thread; ~16us of
//      store latency). Main loop, attn (R13), gemm2, prep frozen.
// ---------------------------------------------------------------------------

typedef short          bf16x8 __attribute__((ext_vector_type(8)));
typedef float          f32x4  __attribute__((ext_vector_type(4)));
typedef unsigned short u16x4  __attribute__((ext_vector_type(4)));
typedef unsigned short u16x8  __attribute__((ext_vector_type(8)));

#define B_   2
#define L_   2048
#define D_   1024
#define H_   16
#define HD_  64
#define BL_  4096           // B_*L_
#define LOG2E 1.4426950408889634f
#define QSC  0.18033688011112042f   // 0.125 * LOG2E (scale+log2e folded into Q)

__device__ __forceinline__ unsigned short f2bf(float f) {   // RNE f32->bf16
  unsigned int u = __float_as_uint(f);
  u += 0x7FFFu + ((u >> 16) & 1u);
  return (unsigned short)(u >> 16);
}
__device__ __forceinline__ float bf2f(unsigned short h) {
  return __uint_as_float(((unsigned int)h) << 16);
}
__device__ __forceinline__ uint32_t cvtpk_bf16(float lo, float hi) {
  uint32_t r;
  asm("v_cvt_pk_bf16_f32 %0, %1, %2" : "=v"(r) : "v"(lo), "v"(hi));
  return r;
}
// raw v_exp_f32: D = 2^S0 (~1 ulp; inputs here are |x| < ~40, no edge cases)
__device__ __forceinline__ float fast_exp2(float x) {
  float r;
  asm("v_exp_f32 %0, %1" : "=v"(r) : "v"(x));
  return r;
}

// async global->LDS, 16B per lane; LDS dest is wave-uniform base + lane*16
__device__ __forceinline__ void gload_lds16(const unsigned short* g, unsigned short* l) {
  __builtin_amdgcn_global_load_lds(
      (__attribute__((address_space(1))) void*)g,
      (__attribute__((address_space(3))) void*)l, 16, 0, 0);
}

// ---------------------------------------------------------------------------
// Fused preprocessing (frozen): one kernel, range-partitioned grid.
// ---------------------------------------------------------------------------
__device__ __forceinline__ void transpose_tile(
    const float* __restrict__ src, unsigned short* __restrict__ dst,
    int K, int N, int n0, int k0, int tid, float (*tile)[33]) {
  const int tx = tid & 31, ty = tid >> 5;   // (32,8)
#pragma unroll
  for (int i = 0; i < 4; ++i)
    tile[ty * 4 + i][tx] = src[(size_t)(k0 + ty * 4 + i) * N + n0 + tx];
  __syncthreads();
#pragma unroll
  for (int i = 0; i < 4; ++i)
    dst[(size_t)(n0 + ty * 4 + i) * K + k0 + tx] = f2bf(tile[tx][ty * 4 + i]);
}

__global__ void __launch_bounds__(256)
prep_kernel(const float* __restrict__ x,
            const float* __restrict__ Wqkv,
            const float* __restrict__ Wout,
            u16x8* __restrict__ xb,
            unsigned short* __restrict__ WqkvT,
            unsigned short* __restrict__ WoutT,
            float2* __restrict__ rtbl) {
  __shared__ float tile[32][33];
  const int bid = blockIdx.x, tid = threadIdx.x;
  if (bid < 2048) {                       // cast x -> bf16
    const int i = bid * 256 + tid;        // 524288 total, exact
    const float4 a = ((const float4*)x)[2 * i];
    const float4 b = ((const float4*)x)[2 * i + 1];
    u16x8 o;
    o[0] = f2bf(a.x); o[1] = f2bf(a.y); o[2] = f2bf(a.z); o[3] = f2bf(a.w);
    o[4] = f2bf(b.x); o[5] = f2bf(b.y); o[6] = f2bf(b.z); o[7] = f2bf(b.w);
    xb[i] = o;
  } else if (bid < 2304) {                // RoPE table
    const int i = (bid - 2048) * 256 + tid;   // 65536
    const int pos = i >> 5, j = i & 31;
    const float inv = exp2f(-(float)j * 0.4152410118609203f);   // log2(1e4)/32
    float s, c;
    sincosf((float)pos * inv, &s, &c);
    rtbl[i] = make_float2(c, s);
  } else if (bid < 5376) {                // Wqkv transpose
    const int t = bid - 2304;             // 96 x 32
    transpose_tile(Wqkv, WqkvT, D_, 3 * D_, (t % 96) * 32, (t / 96) * 32, tid, tile);
  } else {                                // Wout transpose
    const int t = bid - 5376;             // 32 x 32
    transpose_tile(Wout, WoutT, D_, D_, (t % 32) * 32, (t / 32) * 32, tid, tile);
  }
}

// ---------------------------------------------------------------------------
// gemm_bt3 (R16 loop + R17 epilogue): C = A * Bt^T + bias.
// 128x128 tile, BK=64, 4 waves (2x2, 64x64 out each). Rows = 128B ->
// (row&7)<<4 XOR swizzle (0 conflicts measured). LDS 64KB -> 2 blocks/CU.
// MODE 0 epilogue: per-wave LDS tile (64x72 u16, reusing As/Bs) staged,
//   then coalesced u16x8 write-out. Q/K: RoPE in-register -> et[row][d];
//   V: sigma applied at LDS-write -> et[d][posS&63]; global linear window.
// MODE 1: fp32 out + bias (unchanged).
// ---------------------------------------------------------------------------
template <int MODE>
__global__ void __launch_bounds__(256)
gemm_bt3(const unsigned short* __restrict__ A,
         const unsigned short* __restrict__ Bt,
         const float* __restrict__ bias,
         const float2* __restrict__ rt,
         float* __restrict__ outF,
         unsigned short* __restrict__ Qb,
         unsigned short* __restrict__ Kb,
         unsigned short* __restrict__ Vt,
         int M, int N, int K) {
  __shared__ unsigned short As[2][8192];   // [buf][128 rows][64 k] bf16, swz
  __shared__ unsigned short Bs[2][8192];
  const int tid = threadIdx.x;
  const int w = tid >> 6, l = tid & 63;
  const int lg = l >> 4, ll = l & 15;
  // T1: XCD-aware remap of the linearized grid (gridDim.x % 8 == 0)
  const int cpx = gridDim.x >> 3;
  const int lid = (blockIdx.x & 7) * cpx + (blockIdx.x >> 3);
  const int nx = N >> 7;
  const int n0 = (lid % nx) * 128, m0 = (lid / nx) * 128;
  const int wm = (w >> 1) * 64, wn = (w & 1) * 64;

  f32x4 acc[4][4] = {};

  // staging: slot idx = c*256 + tid -> row = idx>>3 (0..127), slot = idx&7;
  // source col pre-swizzled (slot ^ (row&7)) so linear-LDS + XOR-read works.
  int srcOff[4];
#pragma unroll
  for (int c = 0; c < 4; ++c) {
    const int idx = c * 256 + tid;
    const int row = idx >> 3, slot = idx & 7;
    srcOff[c] = row * K + ((slot ^ (row & 7)) << 3);   // ushort offset
  }
  const unsigned short* gA = A + (size_t)m0 * K;
  const unsigned short* gB = Bt + (size_t)n0 * K;

  auto stage = [&](int bsel, int kt) {
    const int kk = kt * 64;
#pragma unroll
    for (int c = 0; c < 4; ++c)
      gload_lds16(gA + srcOff[c] + kk, &As[bsel][c * 2048 + w * 512]);
#pragma unroll
    for (int c = 0; c < 4; ++c)
      gload_lds16(gB + srcOff[c] + kk, &Bs[bsel][c * 2048 + w * 512]);
  };

  const int NT = K >> 6;                   // 16
  int buf = 0;

  stage(0, 0);
  for (int kt = 0; kt < NT; ++kt) {
    __syncthreads();                      // drains vmcnt -> staged tile visible
    if (kt + 1 < NT) stage(buf ^ 1, kt + 1);
    const char* pa = (const char*)&As[buf][0];
    const char* pb = (const char*)&Bs[buf][0];
#pragma unroll
    for (int kk = 0; kk < 2; ++kk) {
      bf16x8 af[4], bfv[4];
#pragma unroll
      for (int mi = 0; mi < 4; ++mi) {
        const int row = wm + mi * 16 + ll;
        af[mi] = *(const bf16x8*)(pa + row * 128 +
                                  ((kk * 64 + lg * 16) ^ ((row & 7) << 4)));
      }
#pragma unroll
      for (int ni = 0; ni < 4; ++ni) {
        const int row = wn + ni * 16 + ll;
        bfv[ni] = *(const bf16x8*)(pb + row * 128 +
                                   ((kk * 64 + lg * 16) ^ ((row & 7) << 4)));
      }
      __builtin_amdgcn_s_setprio(1);
#pragma unroll
      for (int mi = 0; mi < 4; ++mi)
#pragma unroll
        for (int ni = 0; ni < 4; ++ni)
          acc[mi][ni] = __builtin_amdgcn_mfma_f32_16x16x32_bf16(
              af[mi], bfv[ni], acc[mi][ni], 0, 0, 0);
      __builtin_amdgcn_s_setprio(0);
    }
    buf ^= 1;
  }

  // epilogue. C layout: row = (l>>4)*4 + reg, col = l&15   (guide m89/m91)
  if (MODE == 0) {
    __syncthreads();                      // all waves done reading As/Bs
    // per-wave staging tile: 64 x 72 u16 (pitch 144B, 16B-aligned rows)
    unsigned short* et = (w < 2 ? &As[0][0] : &Bs[0][0]) + (w & 1) * 4608;
    const int t  = (n0 + wn) >> 10;       // 0=q 1=k 2=v, wave-uniform
    const int bb = (m0 + wm) >> 11;       // batch (wave-uniform)
    const int P0 = (m0 + wm) & 2047;      // 64-aligned pos window base
    const int h  = ((n0 + wn) & 1023) >> 6;
    const int bh = bb * H_ + h;
    if (t == 2) {                         // V: sigma at LDS-write, et[d][posS]
#pragma unroll
      for (int ni = 0; ni < 4; ++ni) {
        const int d = ni * 16 + ll;
        const float bv = bias[n0 + wn + ni * 16 + ll];
#pragma unroll
        for (int mi = 0; mi < 4; ++mi) {
          const int row0 = mi * 16 + lg * 4;        // local pos, 4-aligned
          const int wb = (row0 >> 2) & 7;
          const int posS = (row0 & ~31) + 8 * (wb & 3) + 4 * (wb >> 2);
#pragma unroll
          for (int rg = 0; rg < 4; ++rg)
            et[d * 72 + posS + rg] = f2bf(acc[mi][ni][rg] + bv);
        }
      }
      // same-wave write->read (compiler orders LDS deps); coalesced out
      unsigned short* gbase = Vt + (size_t)bh * HD_ * L_ + P0;
#pragma unroll
      for (int pass = 0; pass < 8; ++pass) {
        const int d = pass * 8 + (l >> 3);
        const int slot = l & 7;
        const u16x8 v = *(const u16x8*)(et + d * 72 + slot * 8);
        *(u16x8*)(gbase + (size_t)d * L_ + slot * 8) = v;
      }
    } else {                              // Q/K: RoPE in-register -> et[row][d]
      unsigned short* dst = (t == 0) ? Qb : Kb;
      const float qsc = (t == 0) ? QSC : 1.0f;
#pragma unroll
      for (int ni = 0; ni < 2; ++ni) {
        const int d = ni * 16 + ll;       // 0..31
        const float bv1 = bias[n0 + wn + ni * 16 + ll];
        const float bv2 = bias[n0 + wn + (ni + 2) * 16 + ll];
#pragma unroll
        for (int mi = 0; mi < 4; ++mi) {
#pragma unroll
          for (int rg = 0; rg < 4; ++rg) {
            const int row = mi * 16 + lg * 4 + rg;  // local pos
            const float2 cs = rt[(P0 + row) * 32 + d];
            const float q1 = acc[mi][ni][rg] + bv1;
            const float q2 = acc[mi][ni + 2][rg] + bv2;
            et[row * 72 + d]      = f2bf((q1 * cs.x - q2 * cs.y) * qsc);
            et[row * 72 + d + 32] = f2bf((q2 * cs.x + q1 * cs.y) * qsc);
          }
        }
      }
      unsigned short* gbase = dst + ((size_t)bh * L_ + P0) * HD_;
#pragma unroll
      for (int pass = 0; pass < 8; ++pass) {
        const int row = pass * 8 + (l >> 3);
        const int slot = l & 7;
        const u16x8 v = *(const u16x8*)(et + row * 72 + slot * 8);
        *(u16x8*)(gbase + (size_t)row * HD_ + slot * 8) = v;
      }
    }
  } else {
#pragma unroll
    for (int ni = 0; ni < 4; ++ni) {
      const int n = n0 + wn + ni * 16 + ll;
      const float bv = bias[n];
#pragma unroll
      for (int mi = 0; mi < 4; ++mi) {
        const int row0 = m0 + wm + mi * 16 + lg * 4;
#pragma unroll
        for (int rg = 0; rg < 4; ++rg)
          outF[(size_t)(row0 + rg) * N + n] = acc[mi][ni][rg] + bv;
      }
    }
  }
}

// ---------------------------------------------------------------------------
// Flash attention (R13, frozen): 8 waves x 16 q-rows; KVBLK=128 as 2x[64][64]
// chunks; swapped QK^T; in-register P; sigma-permuted Vt; no-max softmax;
// raw v_exp_f32; row sum via osum = mfma(pa, ones).
// ---------------------------------------------------------------------------
__global__ void __launch_bounds__(512)
attn_kernel(const unsigned short* __restrict__ Qb,
            const unsigned short* __restrict__ Kb,
            const unsigned short* __restrict__ Vt,
            unsigned short* __restrict__ Ob) {
  __shared__ unsigned short Ks[2][2][4096];  // [buf][kc][kv 64][d 64], swizzled
  __shared__ unsigned short Vs[2][2][4096];  // [buf][kc][d 64][kv' 64], swizzled
  const int tid = threadIdx.x, w = tid >> 6, l = tid & 63;
  const int lg = l >> 4, ll = l & 15;
  const int bid = ((blockIdx.x & 7) << 6) + (blockIdx.x >> 3);
  const int bh  = bid >> 4;
  const int q0  = (bid & 15) * 128;
  const unsigned short* Qp = Qb + ((size_t)bh * L_ + q0 + w * 16) * HD_;
  const unsigned short* Kp = Kb + (size_t)bh * L_ * HD_;
  const unsigned short* Vp = Vt + (size_t)bh * HD_ * L_;

  const int srow = tid >> 3;
  const int scol = ((tid & 7) ^ (srow & 7)) * 8;
  auto stage = [&](int bsel, int kv0) {
#pragma unroll
    for (int c = 0; c < 2; ++c) {
      gload_lds16(Kp + (size_t)(kv0 + c * 64 + srow) * HD_ + scol, &Ks[bsel][c][w * 512]);
      gload_lds16(Vp + (size_t)srow * L_ + kv0 + c * 64 + scol, &Vs[bsel][c][w * 512]);
    }
  };

  bf16x8 qf[2];
#pragma unroll
  for (int ks = 0; ks < 2; ++ks)
    qf[ks] = *(const bf16x8*)(Qp + (size_t)ll * HD_ + ks * 32 + 8 * lg);

  bf16x8 ones;
#pragma unroll
  for (int j = 0; j < 8; ++j) ones[j] = (short)0x3F80;

  f32x4 o[4] = {};
  f32x4 osum = {};                           // row-sum acc: osum[rg] for q=lg*4+rg

  stage(0, 0);
  __syncthreads();

  int buf = 0;
  for (int t = 0; t < 16; ++t) {
    if (t + 1 < 16) stage(buf ^ 1, (t + 1) * 128);
    f32x4 s[2][4];

#pragma unroll
    for (int kc = 0; kc < 2; ++kc) {
      const char* Ksb = (const char*)&Ks[buf][kc][0];
      bf16x8 kfr[4][2];
#pragma unroll
      for (int ni = 0; ni < 4; ++ni)
#pragma unroll
        for (int ks = 0; ks < 2; ++ks)
          kfr[ni][ks] = *(const bf16x8*)(Ksb + (ni * 16 + ll) * 128 +
                                         ((ks * 64 + lg * 16) ^ ((ll & 7) << 4)));
#pragma unroll
      for (int ni = 0; ni < 4; ++ni) s[kc][ni] = f32x4{0.f, 0.f, 0.f, 0.f};
      __builtin_amdgcn_s_setprio(1);
#pragma unroll
      for (int ks = 0; ks < 2; ++ks)
#pragma unroll
        for (int ni = 0; ni < 4; ++ni)
          s[kc][ni] = __builtin_amdgcn_mfma_f32_16x16x32_bf16(kfr[ni][ks], qf[ks], s[kc][ni], 0, 0, 0);
      __builtin_amdgcn_s_setprio(0);
    }

    bf16x8 pa[2][2];                       // [kc][ks]
#pragma unroll
    for (int kc = 0; kc < 2; ++kc) {
      uint32_t wd[4][2];
#pragma unroll
      for (int ni = 0; ni < 4; ++ni) {
        const float p0 = fast_exp2(s[kc][ni][0]);
        const float p1 = fast_exp2(s[kc][ni][1]);
        const float p2 = fast_exp2(s[kc][ni][2]);
        const float p3 = fast_exp2(s[kc][ni][3]);
        wd[ni][0] = cvtpk_bf16(p0, p1);
        wd[ni][1] = cvtpk_bf16(p2, p3);
      }
#pragma unroll
      for (int ks = 0; ks < 2; ++ks) {
        union { uint32_t u[4]; bf16x8 v; } pu;
        pu.u[0] = wd[2 * ks][0];     pu.u[1] = wd[2 * ks][1];
        pu.u[2] = wd[2 * ks + 1][0]; pu.u[3] = wd[2 * ks + 1][1];
        pa[kc][ks] = pu.v;
      }
    }

#pragma unroll
    for (int kc = 0; kc < 2; ++kc) {
      const char* Vsb = (const char*)&Vs[buf][kc][0];
      bf16x8 vf[2][4];
#pragma unroll
      for (int ks = 0; ks < 2; ++ks)
#pragma unroll
        for (int ni = 0; ni < 4; ++ni)
          vf[ks][ni] = *(const bf16x8*)(Vsb + (ni * 16 + ll) * 128 +
                                        ((ks * 64 + lg * 16) ^ ((ll & 7) << 4)));
      __builtin_amdgcn_s_setprio(1);
#pragma unroll
      for (int ks = 0; ks < 2; ++ks) {
#pragma unroll
        for (int ni = 0; ni < 4; ++ni)
          o[ni] = __builtin_amdgcn_mfma_f32_16x16x32_bf16(pa[kc][ks], vf[ks][ni], o[ni], 0, 0, 0);
        osum = __builtin_amdgcn_mfma_f32_16x16x32_bf16(pa[kc][ks], ones, osum, 0, 0, 0);
      }
      __builtin_amdgcn_s_setprio(0);
    }

    __syncthreads();
    buf ^= 1;
  }

  const int b = bh >> 4, h = bh & 15;
  unsigned short* Op = Ob + ((size_t)b * L_ + q0 + w * 16) * D_ + h * HD_;
#pragma unroll
  for (int rg = 0; rg < 4; ++rg) {
    const float iq = 1.0f / osum[rg];
#pragma unroll
    for (int ni = 0; ni < 4; ++ni)
      Op[(size_t)(lg * 4 + rg) * D_ + ni * 16 + ll] = f2bf(o[ni][rg] * iq);
  }
}

// ---------------------------------------------------------------------------
extern "C" void kernel_launch(void* const* d_in, const int* in_sizes, int n_in,
                              void* d_out, int out_size, void* d_ws, size_t ws_size,
                              hipStream_t stream) {
  const float* x    = (const float*)d_in[0];
  const float* Wqkv = (const float*)d_in[1];
  const float* bqkv = (const float*)d_in[2];
  const float* Wout = (const float*)d_in[3];
  const float* bout = (const float*)d_in[4];
  float* out = (float*)d_out;

  char* ws = (char*)d_ws;                       // 48 MiB used
  unsigned short* xb    = (unsigned short*)(ws);                    // 8 MiB
  unsigned short* WqkvT = (unsigned short*)(ws + (8ull  << 20));    // 6 MiB
  unsigned short* WoutT = (unsigned short*)(ws + (14ull << 20));    // 2 MiB
  unsigned short* Qb    = (unsigned short*)(ws + (16ull << 20));    // 8 MiB
  unsigned short* Kb    = (unsigned short*)(ws + (24ull << 20));    // 8 MiB
  unsigned short* Vt    = (unsigned short*)(ws + (32ull << 20));    // 8 MiB
  unsigned short* Ob    = (unsigned short*)(ws + (40ull << 20));    // 8 MiB
  float2* rtbl = (float2*)(ws + (40ull << 20));  // aliases Ob (dead by attn)

  prep_kernel<<<6400, 256, 0, stream>>>(x, Wqkv, Wout, (u16x8*)xb, WqkvT, WoutT, rtbl);

  gemm_bt3<0><<<(3 * D_ / 128) * (BL_ / 128), 256, 0, stream>>>(
      xb, WqkvT, bqkv, rtbl, nullptr, Qb, Kb, Vt, BL_, 3 * D_, D_);

  attn_kernel<<<B_ * H_ * (L_ / 128), 512, 0, stream>>>(Qb, Kb, Vt, Ob);

  gemm_bt3<1><<<(D_ / 128) * (BL_ / 128), 256, 0, stream>>>(
      Ob, WoutT, bout, nullptr, out, nullptr, nullptr, nullptr, BL_, D_, D_);
}